// Round 2
// baseline (5117.630 us; speedup 1.0000x reference)
//
#include <hip/hip_runtime.h>

#define N_NODES_C 100000
#define N_REL_C 5
#define FEAT 128
#define TM 64
#define BK 32

// ---------------------------------------------------------------------------
// cnt[r][dst] = number of relation-r edges into dst
// ---------------------------------------------------------------------------
__global__ __launch_bounds__(256) void count_edges(const int* __restrict__ dst,
                                                   const int* __restrict__ et,
                                                   int* __restrict__ cnt, int E) {
    int e = blockIdx.x * 256 + threadIdx.x;
    if (e < E) atomicAdd(&cnt[et[e] * N_NODES_C + dst[e]], 1);
}

__global__ __launch_bounds__(256) void make_inv(const int* __restrict__ cnt,
                                                float* __restrict__ inv, int n) {
    int i = blockIdx.x * 256 + threadIdx.x;
    if (i < n) inv[i] = 1.0f / (float)(cnt[i] > 1 ? cnt[i] : 1);
}

// hist[r] = sum_dst cnt[r][dst]   (5 blocks, block r reduces its relation)
__global__ __launch_bounds__(256) void hist_from_cnt(const int* __restrict__ cnt,
                                                     int* __restrict__ hist) {
    __shared__ int red[256];
    int r = blockIdx.x;
    int s = 0;
    for (int i = threadIdx.x; i < N_NODES_C; i += 256) s += cnt[r * N_NODES_C + i];
    red[threadIdx.x] = s;
    __syncthreads();
    for (int w = 128; w > 0; w >>= 1) {
        if (threadIdx.x < w) red[threadIdx.x] += red[threadIdx.x + w];
        __syncthreads();
    }
    if (threadIdx.x == 0) hist[r] = red[0];
}

// off[0..5] exclusive scan of hist; cursor[r] = off[r]   (1 thread)
__global__ void scan_off(const int* __restrict__ hist, int* __restrict__ off,
                         int* __restrict__ cursor) {
    int acc = 0;
    for (int r = 0; r < N_REL_C; r++) {
        off[r] = acc;
        cursor[r] = acc;
        acc += hist[r];
    }
    off[N_REL_C] = acc;
}

// counting-sort fill: edges grouped by relation into esrc/edst
__global__ __launch_bounds__(256) void partition_edges(const int* __restrict__ src,
                                                       const int* __restrict__ dst,
                                                       const int* __restrict__ et,
                                                       int* __restrict__ cursor,
                                                       int* __restrict__ esrc,
                                                       int* __restrict__ edst, int E) {
    __shared__ int lh[N_REL_C];
    __shared__ int lbase[N_REL_C];
    int tid = threadIdx.x;
    int e = blockIdx.x * 256 + tid;
    if (tid < N_REL_C) lh[tid] = 0;
    __syncthreads();
    int t = 0, s = 0, d = 0, myidx = 0;
    bool valid = (e < E);
    if (valid) {
        t = et[e]; s = src[e]; d = dst[e];
        myidx = atomicAdd(&lh[t], 1);
    }
    __syncthreads();
    if (tid < N_REL_C) lbase[tid] = atomicAdd(&cursor[tid], lh[tid]);
    __syncthreads();
    if (valid) {
        int pos = lbase[t] + myidx;
        esrc[pos] = s;
        edst[pos] = d;
    }
}

// ---------------------------------------------------------------------------
// GEMM: C[n][f] = A[n][:]@B (+bias), A [N][128], B [128][128] row-major.
// 64 nodes x 128 feats per block, 256 threads, 4x8 micro-tile.
// ---------------------------------------------------------------------------
__global__ __launch_bounds__(256) void gemm128(const float* __restrict__ A,
                                               const float* __restrict__ B,
                                               const float* __restrict__ bias,
                                               float* __restrict__ C) {
    __shared__ float As[BK][TM + 4];
    __shared__ float Bs[BK][FEAT];

    const int tid = threadIdx.x;
    const int m0 = blockIdx.x * TM;
    const int trow = tid >> 4;
    const int tcol = tid & 15;

    float acc[4][8];
#pragma unroll
    for (int i = 0; i < 4; i++)
#pragma unroll
        for (int j = 0; j < 8; j++) acc[i][j] = 0.0f;

    for (int kb = 0; kb < FEAT; kb += BK) {
        __syncthreads();
#pragma unroll
        for (int i = 0; i < 2; i++) {
            int idx = tid + i * 256;     // float4 slot; 8 per row
            int m = idx >> 3;
            int kq = (idx & 7) * 4;
            int n = m0 + m;
            int nn = n < N_NODES_C ? n : 0;
            float4 v = *(const float4*)(A + (size_t)nn * FEAT + kb + kq);
            As[kq + 0][m] = v.x;
            As[kq + 1][m] = v.y;
            As[kq + 2][m] = v.z;
            As[kq + 3][m] = v.w;
        }
#pragma unroll
        for (int i = 0; i < 4; i++) {
            int idx = tid + i * 256;     // float4 slot; 32 per row
            int k = idx >> 5;
            int c = (idx & 31) * 4;
            *(float4*)&Bs[k][c] = *(const float4*)(B + (size_t)(kb + k) * FEAT + c);
        }
        __syncthreads();

#pragma unroll
        for (int k = 0; k < BK; k++) {
            float4 a = *(const float4*)&As[k][trow * 4];
            float4 b0 = *(const float4*)&Bs[k][tcol * 4];
            float4 b1 = *(const float4*)&Bs[k][64 + tcol * 4];
            float av[4] = {a.x, a.y, a.z, a.w};
            float bv[8] = {b0.x, b0.y, b0.z, b0.w, b1.x, b1.y, b1.z, b1.w};
#pragma unroll
            for (int i = 0; i < 4; i++)
#pragma unroll
                for (int j = 0; j < 8; j++)
                    acc[i][j] = fmaf(av[i], bv[j], acc[i][j]);
        }
    }

    float4 bb0 = {0, 0, 0, 0}, bb1 = {0, 0, 0, 0};
    if (bias) {
        bb0 = *(const float4*)(bias + tcol * 4);
        bb1 = *(const float4*)(bias + 64 + tcol * 4);
    }
#pragma unroll
    for (int i = 0; i < 4; i++) {
        int n = m0 + trow * 4 + i;
        if (n < N_NODES_C) {
            float4 o0, o1;
            o0.x = acc[i][0] + bb0.x;
            o0.y = acc[i][1] + bb0.y;
            o0.z = acc[i][2] + bb0.z;
            o0.w = acc[i][3] + bb0.w;
            o1.x = acc[i][4] + bb1.x;
            o1.y = acc[i][5] + bb1.y;
            o1.z = acc[i][6] + bb1.z;
            o1.w = acc[i][7] + bb1.w;
            *(float4*)(C + (size_t)n * FEAT + tcol * 4) = o0;
            *(float4*)(C + (size_t)n * FEAT + 64 + tcol * 4) = o1;
        }
    }
}

// ---------------------------------------------------------------------------
// scatter (grid-stride over relation-r edge range):
//   out[dst][:] += msg[src][:] * inv[r][dst]
// one wave per edge iteration, lane handles 2 floats
// ---------------------------------------------------------------------------
__global__ __launch_bounds__(256) void scatter_rel(const float* __restrict__ msg,
                                                   const int* __restrict__ esrc,
                                                   const int* __restrict__ edst,
                                                   const int* __restrict__ off, int r,
                                                   const float* __restrict__ inv,
                                                   float* __restrict__ out) {
    int lo = off[r], hi = off[r + 1];
    int lane = threadIdx.x & 63;
    int wid = (blockIdx.x * 256 + threadIdx.x) >> 6;
    int nw = (gridDim.x * 256) >> 6;
    const float* invr = inv + (size_t)r * N_NODES_C;
    for (int e = lo + wid; e < hi; e += nw) {
        int s = esrc[e], d = edst[e];
        float sc = invr[d];
        float2 v = *(const float2*)(msg + (size_t)s * FEAT + lane * 2);
        float* op = out + (size_t)d * FEAT + lane * 2;
        atomicAdd(op, v.x * sc);
        atomicAdd(op + 1, v.y * sc);
    }
}

__global__ __launch_bounds__(256) void relu_inplace(float* __restrict__ p, int n4) {
    int i = blockIdx.x * 256 + threadIdx.x;
    if (i < n4) {
        float4 v = ((float4*)p)[i];
        v.x = fmaxf(v.x, 0.0f);
        v.y = fmaxf(v.y, 0.0f);
        v.z = fmaxf(v.z, 0.0f);
        v.w = fmaxf(v.w, 0.0f);
        ((float4*)p)[i] = v;
    }
}

// ---------------------------------------------------------------------------
extern "C" void kernel_launch(void* const* d_in, const int* in_sizes, int n_in,
                              void* d_out, int out_size, void* d_ws, size_t ws_size,
                              hipStream_t stream) {
    const float* x = (const float*)d_in[0];
    const int* ei  = (const int*)d_in[1];
    const int* et  = (const int*)d_in[2];
    const int E = in_sizes[2];
    const int* src  = ei;       // edge_index[0]
    const int* dstp = ei + E;   // edge_index[1]

    // workspace layout (bytes), total ~119.4 MB:
    //   cnt    @ 0          (2,000,000)
    //   inv    @ 2,097,152  (2,000,000)
    //   hist/off/cursor @ 4,194,304 (hist[5], off[6], cursor[5] -> 64 B)
    //   esrc   @ 4,195,328  (6,400,000)
    //   edst   @ 10,595,328 (6,400,000)
    //   msg    @ 16,995,328 (51,200,000)
    //   h1     @ 68,195,328 (51,200,000)
    char* ws = (char*)d_ws;
    int*   cnt    = (int*)ws;
    float* inv    = (float*)(ws + 2097152);
    int*   hist   = (int*)(ws + 4194304);        // 5 ints
    int*   off    = hist + 8;                    // 6 ints
    int*   cursor = hist + 16;                   // 5 ints
    int*   esrc   = (int*)(ws + 4195328);
    int*   edst   = (int*)(ws + 10595328);
    float* msg    = (float*)(ws + 16995328);
    float* h1     = (float*)(ws + 68195328);

    const int NR = N_REL_C * N_NODES_C;
    hipMemsetAsync(cnt, 0, (size_t)NR * 4, stream);
    count_edges<<<(E + 255) / 256, 256, 0, stream>>>(dstp, et, cnt, E);
    make_inv<<<(NR + 255) / 256, 256, 0, stream>>>(cnt, inv, NR);
    hist_from_cnt<<<N_REL_C, 256, 0, stream>>>(cnt, hist);
    scan_off<<<1, 1, 0, stream>>>(hist, off, cursor);
    partition_edges<<<(E + 255) / 256, 256, 0, stream>>>(src, dstp, et, cursor, esrc, edst, E);

    const float* Wp[3] = {(const float*)d_in[3], (const float*)d_in[6], (const float*)d_in[9]};
    const float* Rp[3] = {(const float*)d_in[4], (const float*)d_in[7], (const float*)d_in[10]};
    const float* Bp[3] = {(const float*)d_in[5], (const float*)d_in[8], (const float*)d_in[11]};

    const int gemm_grid = (N_NODES_C + TM - 1) / TM;
    const int n4 = N_NODES_C * FEAT / 4;

    // layer dataflow: x -> d_out -> h1 -> d_out
    const float* hin = x;
    float* houts[3] = {(float*)d_out, h1, (float*)d_out};
    for (int l = 0; l < 3; l++) {
        float* o = houts[l];
        gemm128<<<gemm_grid, 256, 0, stream>>>(hin, Rp[l], Bp[l], o);
        for (int r = 0; r < N_REL_C; r++) {
            gemm128<<<gemm_grid, 256, 0, stream>>>(hin, Wp[l] + (size_t)r * FEAT * FEAT,
                                                   nullptr, msg);
            scatter_rel<<<2048, 256, 0, stream>>>(msg, esrc, edst, off, r, inv, o);
        }
        relu_inplace<<<(n4 + 255) / 256, 256, 0, stream>>>(o, n4);
        hin = o;
    }
}

// Round 3
// 1968.532 us; speedup vs baseline: 2.5997x; 2.5997x over previous
//
#include <hip/hip_runtime.h>

#define N_NODES_C 100000
#define N_REL_C 5
#define N_TOT (N_REL_C * N_NODES_C)
#define FEAT 128
#define TM 64
#define BK 32

// ---------------------------------------------------------------------------
// cnt[r][dst] = number of relation-r edges into dst
// ---------------------------------------------------------------------------
__global__ __launch_bounds__(256) void count_edges(const int* __restrict__ dst,
                                                   const int* __restrict__ et,
                                                   int* __restrict__ cnt, int E) {
    int e = blockIdx.x * 256 + threadIdx.x;
    if (e < E) atomicAdd(&cnt[et[e] * N_NODES_C + dst[e]], 1);
}

__global__ __launch_bounds__(256) void make_inv(const int* __restrict__ cnt,
                                                float* __restrict__ inv, int n) {
    int i = blockIdx.x * 256 + threadIdx.x;
    if (i < n) inv[i] = 1.0f / (float)(cnt[i] > 1 ? cnt[i] : 1);
}

// ---------------------------------------------------------------------------
// device-wide exclusive scan of cnt[0..n) -> rowptr  (3-kernel, 256/block)
// ---------------------------------------------------------------------------
__global__ __launch_bounds__(256) void scan_block(const int* __restrict__ cnt,
                                                  int* __restrict__ rowptr,
                                                  int* __restrict__ bsum, int n) {
    __shared__ int sh[256];
    int tid = threadIdx.x;
    int i = blockIdx.x * 256 + tid;
    int v = (i < n) ? cnt[i] : 0;
    sh[tid] = v;
    __syncthreads();
#pragma unroll
    for (int o = 1; o < 256; o <<= 1) {
        int t = (tid >= o) ? sh[tid - o] : 0;
        __syncthreads();
        sh[tid] += t;
        __syncthreads();
    }
    if (i < n) rowptr[i] = sh[tid] - v;   // exclusive
    if (tid == 255) bsum[blockIdx.x] = sh[255];
}

__global__ __launch_bounds__(256) void scan_bsum(int* __restrict__ bsum, int nb) {
    __shared__ int sh[256];
    __shared__ int carry;
    int tid = threadIdx.x;
    if (tid == 0) carry = 0;
    __syncthreads();
    for (int base = 0; base < nb; base += 256) {
        int i = base + tid;
        int v = (i < nb) ? bsum[i] : 0;
        sh[tid] = v;
        __syncthreads();
#pragma unroll
        for (int o = 1; o < 256; o <<= 1) {
            int t = (tid >= o) ? sh[tid - o] : 0;
            __syncthreads();
            sh[tid] += t;
            __syncthreads();
        }
        int excl = sh[tid] - v + carry;      // reads carry
        int chunk_total = sh[255];
        __syncthreads();                     // all reads of carry done
        if (i < nb) bsum[i] = excl;
        if (tid == 0) carry += chunk_total;
        __syncthreads();
    }
}

__global__ __launch_bounds__(256) void scan_add(int* __restrict__ rowptr,
                                                const int* __restrict__ bsum,
                                                int n, int Etot) {
    int i = blockIdx.x * 256 + threadIdx.x;
    if (i < n) rowptr[i] += bsum[blockIdx.x];
    if (i == 0) rowptr[n] = Etot;
}

// fill CSR: esrc grouped by (relation, dst)
__global__ __launch_bounds__(256) void fill_csr(const int* __restrict__ src,
                                                const int* __restrict__ dst,
                                                const int* __restrict__ et,
                                                int* __restrict__ cursor,
                                                int* __restrict__ esrc, int E) {
    int e = blockIdx.x * 256 + threadIdx.x;
    if (e < E) {
        int pos = atomicAdd(&cursor[et[e] * N_NODES_C + dst[e]], 1);
        esrc[pos] = src[e];
    }
}

// ---------------------------------------------------------------------------
// GEMM: C[n][f] = A[n][:]@B (+bias), A [N][128], B [128][128] row-major.
// 64 nodes x 128 feats per block, 256 threads, 4x8 micro-tile.
// ---------------------------------------------------------------------------
__global__ __launch_bounds__(256) void gemm128(const float* __restrict__ A,
                                               const float* __restrict__ B,
                                               const float* __restrict__ bias,
                                               float* __restrict__ C) {
    __shared__ float As[BK][TM + 4];
    __shared__ float Bs[BK][FEAT];

    const int tid = threadIdx.x;
    const int m0 = blockIdx.x * TM;
    const int trow = tid >> 4;
    const int tcol = tid & 15;

    float acc[4][8];
#pragma unroll
    for (int i = 0; i < 4; i++)
#pragma unroll
        for (int j = 0; j < 8; j++) acc[i][j] = 0.0f;

    for (int kb = 0; kb < FEAT; kb += BK) {
        __syncthreads();
#pragma unroll
        for (int i = 0; i < 2; i++) {
            int idx = tid + i * 256;     // float4 slot; 8 per row
            int m = idx >> 3;
            int kq = (idx & 7) * 4;
            int n = m0 + m;
            int nn = n < N_NODES_C ? n : 0;
            float4 v = *(const float4*)(A + (size_t)nn * FEAT + kb + kq);
            As[kq + 0][m] = v.x;
            As[kq + 1][m] = v.y;
            As[kq + 2][m] = v.z;
            As[kq + 3][m] = v.w;
        }
#pragma unroll
        for (int i = 0; i < 4; i++) {
            int idx = tid + i * 256;     // float4 slot; 32 per row
            int k = idx >> 5;
            int c = (idx & 31) * 4;
            *(float4*)&Bs[k][c] = *(const float4*)(B + (size_t)(kb + k) * FEAT + c);
        }
        __syncthreads();

#pragma unroll
        for (int k = 0; k < BK; k++) {
            float4 a = *(const float4*)&As[k][trow * 4];
            float4 b0 = *(const float4*)&Bs[k][tcol * 4];
            float4 b1 = *(const float4*)&Bs[k][64 + tcol * 4];
            float av[4] = {a.x, a.y, a.z, a.w};
            float bv[8] = {b0.x, b0.y, b0.z, b0.w, b1.x, b1.y, b1.z, b1.w};
#pragma unroll
            for (int i = 0; i < 4; i++)
#pragma unroll
                for (int j = 0; j < 8; j++)
                    acc[i][j] = fmaf(av[i], bv[j], acc[i][j]);
        }
    }

    float4 bb0 = {0, 0, 0, 0}, bb1 = {0, 0, 0, 0};
    if (bias) {
        bb0 = *(const float4*)(bias + tcol * 4);
        bb1 = *(const float4*)(bias + 64 + tcol * 4);
    }
#pragma unroll
    for (int i = 0; i < 4; i++) {
        int n = m0 + trow * 4 + i;
        if (n < N_NODES_C) {
            float4 o0, o1;
            o0.x = acc[i][0] + bb0.x;
            o0.y = acc[i][1] + bb0.y;
            o0.z = acc[i][2] + bb0.z;
            o0.w = acc[i][3] + bb0.w;
            o1.x = acc[i][4] + bb1.x;
            o1.y = acc[i][5] + bb1.y;
            o1.z = acc[i][6] + bb1.z;
            o1.w = acc[i][7] + bb1.w;
            *(float4*)(C + (size_t)n * FEAT + tcol * 4) = o0;
            *(float4*)(C + (size_t)n * FEAT + 64 + tcol * 4) = o1;
        }
    }
}

// ---------------------------------------------------------------------------
// gather (per relation): one wave per dst node, lane = 2 floats.
//   out[node][:] += (sum_{e in CSR[node]} msg[esrc[e]][:]) * invr[node]
// Non-atomic out RMW: exactly one wave owns each node.
// ---------------------------------------------------------------------------
__global__ __launch_bounds__(256) void gather_rel(const float* __restrict__ msg,
                                                  const int* __restrict__ esrc,
                                                  const int* __restrict__ rowptr,
                                                  const float* __restrict__ invr,
                                                  float* __restrict__ out) {
    int node = blockIdx.x * 4 + (threadIdx.x >> 6);
    int lane = threadIdx.x & 63;
    if (node >= N_NODES_C) return;
    int lo = rowptr[node], hi = rowptr[node + 1];
    if (lo == hi) return;
    float2 acc = {0.0f, 0.0f};
    for (int e = lo; e < hi; e++) {
        int s = esrc[e];                       // wave-uniform load (broadcast)
        float2 v = *(const float2*)(msg + (size_t)s * FEAT + lane * 2);
        acc.x += v.x;
        acc.y += v.y;
    }
    float sc = invr[node];
    float2* op = (float2*)(out + (size_t)node * FEAT + lane * 2);
    float2 o = *op;
    o.x += acc.x * sc;
    o.y += acc.y * sc;
    *op = o;
}

__global__ __launch_bounds__(256) void relu_inplace(float* __restrict__ p, int n4) {
    int i = blockIdx.x * 256 + threadIdx.x;
    if (i < n4) {
        float4 v = ((float4*)p)[i];
        v.x = fmaxf(v.x, 0.0f);
        v.y = fmaxf(v.y, 0.0f);
        v.z = fmaxf(v.z, 0.0f);
        v.w = fmaxf(v.w, 0.0f);
        ((float4*)p)[i] = v;
    }
}

// ---------------------------------------------------------------------------
extern "C" void kernel_launch(void* const* d_in, const int* in_sizes, int n_in,
                              void* d_out, int out_size, void* d_ws, size_t ws_size,
                              hipStream_t stream) {
    const float* x = (const float*)d_in[0];
    const int* ei  = (const int*)d_in[1];
    const int* et  = (const int*)d_in[2];
    const int E = in_sizes[2];
    const int* src  = ei;       // edge_index[0]
    const int* dstp = ei + E;   // edge_index[1]

    // workspace layout (bytes), total ~119.4 MB:
    //   cnt    @ 0           (2,000,000)
    //   inv    @ 2,097,152   (2,000,000)
    //   rowptr @ 4,194,304   (2,000,004)
    //   cursor @ 6,291,456   (2,000,000)
    //   bsum   @ 8,388,608   (~8 KB)
    //   esrc   @ 8,650,752   (6,400,000)
    //   msg    @ 16,777,216  (51,200,000)
    //   h1     @ 68,157,440  (51,200,000)
    char* ws = (char*)d_ws;
    int*   cnt    = (int*)ws;
    float* inv    = (float*)(ws + 2097152);
    int*   rowptr = (int*)(ws + 4194304);
    int*   cursor = (int*)(ws + 6291456);
    int*   bsum   = (int*)(ws + 8388608);
    int*   esrc   = (int*)(ws + 8650752);
    float* msg    = (float*)(ws + 16777216);
    float* h1     = (float*)(ws + 68157440);

    const int nscan_blocks = (N_TOT + 255) / 256;   // 1954

    hipMemsetAsync(cnt, 0, (size_t)N_TOT * 4, stream);
    count_edges<<<(E + 255) / 256, 256, 0, stream>>>(dstp, et, cnt, E);
    make_inv<<<(N_TOT + 255) / 256, 256, 0, stream>>>(cnt, inv, N_TOT);
    scan_block<<<nscan_blocks, 256, 0, stream>>>(cnt, rowptr, bsum, N_TOT);
    scan_bsum<<<1, 256, 0, stream>>>(bsum, nscan_blocks);
    scan_add<<<nscan_blocks, 256, 0, stream>>>(rowptr, bsum, N_TOT, E);
    hipMemcpyAsync(cursor, rowptr, (size_t)N_TOT * 4, hipMemcpyDeviceToDevice, stream);
    fill_csr<<<(E + 255) / 256, 256, 0, stream>>>(src, dstp, et, cursor, esrc, E);

    const float* Wp[3] = {(const float*)d_in[3], (const float*)d_in[6], (const float*)d_in[9]};
    const float* Rp[3] = {(const float*)d_in[4], (const float*)d_in[7], (const float*)d_in[10]};
    const float* Bp[3] = {(const float*)d_in[5], (const float*)d_in[8], (const float*)d_in[11]};

    const int gemm_grid = (N_NODES_C + TM - 1) / TM;
    const int gather_grid = (N_NODES_C + 3) / 4;
    const int n4 = N_NODES_C * FEAT / 4;

    // layer dataflow: x -> d_out -> h1 -> d_out
    const float* hin = x;
    float* houts[3] = {(float*)d_out, h1, (float*)d_out};
    for (int l = 0; l < 3; l++) {
        float* o = houts[l];
        gemm128<<<gemm_grid, 256, 0, stream>>>(hin, Rp[l], Bp[l], o);
        for (int r = 0; r < N_REL_C; r++) {
            gemm128<<<gemm_grid, 256, 0, stream>>>(hin, Wp[l] + (size_t)r * FEAT * FEAT,
                                                   nullptr, msg);
            gather_rel<<<gather_grid, 256, 0, stream>>>(msg, esrc,
                                                        rowptr + (size_t)r * N_NODES_C,
                                                        inv + (size_t)r * N_NODES_C, o);
        }
        relu_inplace<<<(n4 + 255) / 256, 256, 0, stream>>>(o, n4);
        hin = o;
    }
}

// Round 4
// 1289.081 us; speedup vs baseline: 3.9700x; 1.5271x over previous
//
#include <hip/hip_runtime.h>

#define N_NODES_C 100000
#define N_REL_C 5
#define N_TOT (N_REL_C * N_NODES_C)
#define FEAT 128
#define CH 25000        // node chunk (agg buffer covers one chunk)
#define NCHUNK 4
#define KTOT 768        // virtual K = 128 (root) + 5*128 (relations)
#define BK 32
#define BM 128          // GEMM block rows
#define LDA 40          // LDS row stride in ushorts: 80 B = 16B-aligned, 2-way banks (free)

typedef __attribute__((ext_vector_type(8))) short bf16x8;
typedef __attribute__((ext_vector_type(4))) float f32x4;

__device__ inline unsigned short f2bf(float f) {
    union { float f; unsigned int u; } v; v.f = f;
    return (unsigned short)((v.u + 0x7FFFu + ((v.u >> 16) & 1u)) >> 16);
}

// ---------------------------------------------------------------------------
// preprocessing (unchanged from round 2): counts, inv, scan -> CSR
// ---------------------------------------------------------------------------
__global__ __launch_bounds__(256) void count_edges(const int* __restrict__ dst,
                                                   const int* __restrict__ et,
                                                   int* __restrict__ cnt, int E) {
    int e = blockIdx.x * 256 + threadIdx.x;
    if (e < E) atomicAdd(&cnt[et[e] * N_NODES_C + dst[e]], 1);
}

__global__ __launch_bounds__(256) void make_inv(const int* __restrict__ cnt,
                                                float* __restrict__ inv, int n) {
    int i = blockIdx.x * 256 + threadIdx.x;
    if (i < n) inv[i] = 1.0f / (float)(cnt[i] > 1 ? cnt[i] : 1);
}

__global__ __launch_bounds__(256) void scan_block(const int* __restrict__ cnt,
                                                  int* __restrict__ rowptr,
                                                  int* __restrict__ bsum, int n) {
    __shared__ int sh[256];
    int tid = threadIdx.x;
    int i = blockIdx.x * 256 + tid;
    int v = (i < n) ? cnt[i] : 0;
    sh[tid] = v;
    __syncthreads();
#pragma unroll
    for (int o = 1; o < 256; o <<= 1) {
        int t = (tid >= o) ? sh[tid - o] : 0;
        __syncthreads();
        sh[tid] += t;
        __syncthreads();
    }
    if (i < n) rowptr[i] = sh[tid] - v;
    if (tid == 255) bsum[blockIdx.x] = sh[255];
}

__global__ __launch_bounds__(256) void scan_bsum(int* __restrict__ bsum, int nb) {
    __shared__ int sh[256];
    __shared__ int carry;
    int tid = threadIdx.x;
    if (tid == 0) carry = 0;
    __syncthreads();
    for (int base = 0; base < nb; base += 256) {
        int i = base + tid;
        int v = (i < nb) ? bsum[i] : 0;
        sh[tid] = v;
        __syncthreads();
#pragma unroll
        for (int o = 1; o < 256; o <<= 1) {
            int t = (tid >= o) ? sh[tid - o] : 0;
            __syncthreads();
            sh[tid] += t;
            __syncthreads();
        }
        int excl = sh[tid] - v + carry;
        int chunk_total = sh[255];
        __syncthreads();
        if (i < nb) bsum[i] = excl;
        if (tid == 0) carry += chunk_total;
        __syncthreads();
    }
}

__global__ __launch_bounds__(256) void scan_add(int* __restrict__ rowptr,
                                                const int* __restrict__ bsum,
                                                int n, int Etot) {
    int i = blockIdx.x * 256 + threadIdx.x;
    if (i < n) rowptr[i] += bsum[blockIdx.x];
    if (i == 0) rowptr[n] = Etot;
}

__global__ __launch_bounds__(256) void fill_csr(const int* __restrict__ src,
                                                const int* __restrict__ dst,
                                                const int* __restrict__ et,
                                                int* __restrict__ cursor,
                                                int* __restrict__ esrc, int E) {
    int e = blockIdx.x * 256 + threadIdx.x;
    if (e < E) {
        int pos = atomicAdd(&cursor[et[e] * N_NODES_C + dst[e]], 1);
        esrc[pos] = src[e];
    }
}

// ---------------------------------------------------------------------------
// conversions to bf16
// ---------------------------------------------------------------------------
__global__ __launch_bounds__(256) void convert_x(const float* __restrict__ x,
                                                 unsigned short* __restrict__ xb, int n4) {
    int i = blockIdx.x * 256 + threadIdx.x;
    if (i >= n4) return;
    float4 v = ((const float4*)x)[i];
    ushort4 o;
    o.x = f2bf(v.x); o.y = f2bf(v.y); o.z = f2bf(v.z); o.w = f2bf(v.w);
    ((ushort4*)xb)[i] = o;
}

// Bt[c][kv] (col-major over virtual K): kv<128 -> root[kv][c]; else W[r][kk][c]
__global__ __launch_bounds__(256) void convert_w(const float* __restrict__ root,
                                                 const float* __restrict__ W,
                                                 unsigned short* __restrict__ Bt) {
    int idx = blockIdx.x * 256 + threadIdx.x;
    if (idx >= FEAT * KTOT) return;
    int c = idx / KTOT;
    int kv = idx - c * KTOT;
    float val;
    if (kv < FEAT) {
        val = root[kv * FEAT + c];
    } else {
        int r = (kv - FEAT) >> 7;
        int kk = (kv - FEAT) & 127;
        val = W[((size_t)r * FEAT + kk) * FEAT + c];
    }
    Bt[idx] = f2bf(val);
}

// ---------------------------------------------------------------------------
// gather: agg[r][local][:] = mean over CSR[r][node] of hb[src][:]  (bf16 out)
// one wave per (relation, node); lane = 2 feats (4B loads/stores)
// ---------------------------------------------------------------------------
__global__ __launch_bounds__(256) void gather_mean(const unsigned short* __restrict__ hb,
                                                   const int* __restrict__ esrc,
                                                   const int* __restrict__ rowptr,
                                                   const float* __restrict__ inv,
                                                   unsigned short* __restrict__ agg,
                                                   int chunk0) {
    int w = threadIdx.x >> 6;
    int lane = threadIdx.x & 63;
    int local = blockIdx.x * 4 + w;
    int r = blockIdx.y;
    int node = chunk0 + local;
    int lo = rowptr[r * N_NODES_C + node];
    int hi = rowptr[r * N_NODES_C + node + 1];
    float a0 = 0.f, a1 = 0.f;
    for (int e = lo; e < hi; e++) {
        int s = esrc[e];
        unsigned int u = *(const unsigned int*)(hb + ((size_t)s << 7) + lane * 2);
        union { unsigned int u; float f; } hv; hv.u = u & 0xFFFF0000u;
        union { unsigned int u; float f; } lv; lv.u = u << 16;
        a0 += lv.f;
        a1 += hv.f;
    }
    float sc = inv[r * N_NODES_C + node];
    unsigned int o = ((unsigned int)f2bf(a1 * sc) << 16) | (unsigned int)f2bf(a0 * sc);
    *(unsigned int*)(agg + ((size_t)(r * CH + local) << 7) + lane * 2) = o;
}

// ---------------------------------------------------------------------------
// MFMA GEMM: C[n][0:128] = relu( A_virt[n][0:768] @ B + bias )
//   A_virt k<128 -> hb[node][k]; k>=128 -> agg[r][local][k%128] (pre-scaled means)
// Block 128 rows x 128 cols, 4 waves in 2x2, wave tile 64x64 (4x4 MFMA tiles).
// Writes fp32 (last layer) or bf16 (hidden layers).
// ---------------------------------------------------------------------------
__global__ __launch_bounds__(256) void rgcn_gemm(const unsigned short* __restrict__ hb,
                                                 const unsigned short* __restrict__ agg,
                                                 const unsigned short* __restrict__ Bt,
                                                 const float* __restrict__ bias,
                                                 float* __restrict__ outf,
                                                 unsigned short* __restrict__ outb,
                                                 int chunk0) {
    __shared__ unsigned short As[BM * LDA];
    __shared__ unsigned short Bs[FEAT * LDA];

    const int tid = threadIdx.x;
    const int w = tid >> 6, lane = tid & 63;
    const int wr = w >> 1, wc = w & 1;
    const int brow0 = blockIdx.x * BM;      // local row base within chunk
    const int lq = lane >> 4;               // quad 0..3
    const int lm = lane & 15;

    f32x4 acc[4][4];
#pragma unroll
    for (int i = 0; i < 4; i++)
#pragma unroll
        for (int j = 0; j < 4; j++) acc[i][j] = (f32x4){0.f, 0.f, 0.f, 0.f};

    // staging: thread -> (row 0..127, seg 0/16 ushorts)
    const int arow = tid >> 1;
    const int aseg = (tid & 1) * 16;
    int lrow = brow0 + arow;
    if (lrow >= CH) lrow = CH - 1;
    const size_t hbrow = (size_t)(chunk0 + lrow) << 7;

    for (int kb = 0; kb < KTOT; kb += BK) {
        __syncthreads();
        const unsigned short* asrc;
        if (kb < FEAT) {
            asrc = hb + hbrow + kb + aseg;
        } else {
            int r = (kb - FEAT) >> 7;
            int kk = (kb - FEAT) & 127;
            asrc = agg + (((size_t)(r * CH + lrow)) << 7) + kk + aseg;
        }
        *(float4*)&As[arow * LDA + aseg]     = *(const float4*)(asrc);
        *(float4*)&As[arow * LDA + aseg + 8] = *(const float4*)(asrc + 8);
        const unsigned short* bsrc = Bt + (size_t)arow * KTOT + kb + aseg;
        *(float4*)&Bs[arow * LDA + aseg]     = *(const float4*)(bsrc);
        *(float4*)&Bs[arow * LDA + aseg + 8] = *(const float4*)(bsrc + 8);
        __syncthreads();

        bf16x8 af[4], bf[4];
#pragma unroll
        for (int t = 0; t < 4; t++) {
            int row = wr * 64 + t * 16 + lm;
            af[t] = *(const bf16x8*)&As[row * LDA + lq * 8];
            int col = wc * 64 + t * 16 + lm;
            bf[t] = *(const bf16x8*)&Bs[col * LDA + lq * 8];
        }
#pragma unroll
        for (int i = 0; i < 4; i++)
#pragma unroll
            for (int j = 0; j < 4; j++)
                acc[i][j] = __builtin_amdgcn_mfma_f32_16x16x32_bf16(af[i], bf[j], acc[i][j], 0, 0, 0);
    }

    float bcol[4];
#pragma unroll
    for (int j = 0; j < 4; j++) bcol[j] = bias[wc * 64 + j * 16 + lm];

#pragma unroll
    for (int i = 0; i < 4; i++) {
#pragma unroll
        for (int reg = 0; reg < 4; reg++) {
            int lr = brow0 + wr * 64 + i * 16 + lq * 4 + reg;
            if (lr < CH) {
                size_t grow = (size_t)(chunk0 + lr) << 7;
#pragma unroll
                for (int j = 0; j < 4; j++) {
                    float v = acc[i][j][reg] + bcol[j];
                    v = fmaxf(v, 0.f);
                    int col = wc * 64 + j * 16 + lm;
                    if (outf) outf[grow + col] = v;
                    else outb[grow + col] = f2bf(v);
                }
            }
        }
    }
}

// ---------------------------------------------------------------------------
extern "C" void kernel_launch(void* const* d_in, const int* in_sizes, int n_in,
                              void* d_out, int out_size, void* d_ws, size_t ws_size,
                              hipStream_t stream) {
    const float* x = (const float*)d_in[0];
    const int* ei  = (const int*)d_in[1];
    const int* et  = (const int*)d_in[2];
    const int E = in_sizes[2];
    const int* src  = ei;
    const int* dstp = ei + E;

    // workspace layout (~95.1 MB total):
    //   inv    @ 0           (2,000,000)
    //   rowptr @ 2,097,152   (2,000,004)
    //   esrc   @ 4,194,304   (6,400,000)
    //   xbA    @ 10,616,832  (25,600,000)
    //   xbB    @ 36,306,944  (25,600,000)
    //   agg    @ 61,997,056  (32,000,000)   [cnt/cursor/bsum alias here, dead before gathers]
    //   Bt     @ 94,502,912  (589,824 = 3 layers x 768x128 bf16)
    char* ws = (char*)d_ws;
    float* inv             = (float*)ws;
    int*   rowptr          = (int*)(ws + 2097152);
    int*   esrc            = (int*)(ws + 4194304);
    unsigned short* xbA    = (unsigned short*)(ws + 10616832);
    unsigned short* xbB    = (unsigned short*)(ws + 36306944);
    unsigned short* agg    = (unsigned short*)(ws + 61997056);
    unsigned short* BtAll  = (unsigned short*)(ws + 94502912);
    int*   cnt    = (int*)(ws + 61997056);             // alias agg
    int*   cursor = (int*)(ws + 61997056 + 2097152);   // alias agg
    int*   bsum   = (int*)(ws + 61997056 + 4194304);   // alias agg

    const int nscan_blocks = (N_TOT + 255) / 256;

    hipMemsetAsync(cnt, 0, (size_t)N_TOT * 4, stream);
    count_edges<<<(E + 255) / 256, 256, 0, stream>>>(dstp, et, cnt, E);
    make_inv<<<(N_TOT + 255) / 256, 256, 0, stream>>>(cnt, inv, N_TOT);
    scan_block<<<nscan_blocks, 256, 0, stream>>>(cnt, rowptr, bsum, N_TOT);
    scan_bsum<<<1, 256, 0, stream>>>(bsum, nscan_blocks);
    scan_add<<<nscan_blocks, 256, 0, stream>>>(rowptr, bsum, N_TOT, E);
    hipMemcpyAsync(cursor, rowptr, (size_t)N_TOT * 4, hipMemcpyDeviceToDevice, stream);
    fill_csr<<<(E + 255) / 256, 256, 0, stream>>>(src, dstp, et, cursor, esrc, E);

    const int n4 = N_NODES_C * FEAT / 4;
    convert_x<<<(n4 + 255) / 256, 256, 0, stream>>>(x, xbA, n4);

    const float* Wp[3] = {(const float*)d_in[3], (const float*)d_in[6], (const float*)d_in[9]};
    const float* Rp[3] = {(const float*)d_in[4], (const float*)d_in[7], (const float*)d_in[10]};
    const float* Bp[3] = {(const float*)d_in[5], (const float*)d_in[8], (const float*)d_in[11]};

    const int nw = FEAT * KTOT;   // 98304
    for (int l = 0; l < 3; l++)
        convert_w<<<(nw + 255) / 256, 256, 0, stream>>>(Rp[l], Wp[l],
                                                        BtAll + (size_t)l * nw);

    const int gemm_grid = (CH + BM - 1) / BM;       // 196
    dim3 ggrid(CH / 4, N_REL_C);                    // 6250 x 5

    // layer dataflow (bf16 ping-pong): xbA -> xbB -> xbA -> d_out(fp32)
    for (int l = 0; l < 3; l++) {
        const unsigned short* hin = (l == 1) ? xbB : xbA;
        unsigned short* outb = (l == 0) ? xbB : ((l == 1) ? xbA : nullptr);
        float* outf = (l == 2) ? (float*)d_out : nullptr;
        for (int c = 0; c < NCHUNK; c++) {
            gather_mean<<<ggrid, 256, 0, stream>>>(hin, esrc, rowptr, inv, agg, c * CH);
            rgcn_gemm<<<gemm_grid, 256, 0, stream>>>(hin, agg, BtAll + (size_t)l * nw,
                                                     Bp[l], outf, outb, c * CH);
        }
    }
}

// Round 5
// 910.872 us; speedup vs baseline: 5.6184x; 1.4152x over previous
//
#include <hip/hip_runtime.h>

#define N_NODES_C 100000
#define N_REL_C 5
#define N_TOT (N_REL_C * N_NODES_C)
#define FEAT 128
#define KTOT 768        // virtual K = 128 (root) + 5*128 (relations)
#define BK 32
#define BM 128          // GEMM block rows
#define LDA 40          // LDS row stride in ushorts: 80 B = 16B-aligned, 2-way banks (free)

typedef __attribute__((ext_vector_type(8))) short bf16x8;
typedef __attribute__((ext_vector_type(4))) float f32x4;

__device__ inline unsigned short f2bf(float f) {
    union { float f; unsigned int u; } v; v.f = f;
    return (unsigned short)((v.u + 0x7FFFu + ((v.u >> 16) & 1u)) >> 16);
}

// ---------------------------------------------------------------------------
// preprocessing: counts, inv, scan -> CSR grouped by (relation, dst)
// ---------------------------------------------------------------------------
__global__ __launch_bounds__(256) void count_edges(const int* __restrict__ dst,
                                                   const int* __restrict__ et,
                                                   int* __restrict__ cnt, int E) {
    int e = blockIdx.x * 256 + threadIdx.x;
    if (e < E) atomicAdd(&cnt[et[e] * N_NODES_C + dst[e]], 1);
}

__global__ __launch_bounds__(256) void make_inv(const int* __restrict__ cnt,
                                                float* __restrict__ inv, int n) {
    int i = blockIdx.x * 256 + threadIdx.x;
    if (i < n) inv[i] = 1.0f / (float)(cnt[i] > 1 ? cnt[i] : 1);
}

__global__ __launch_bounds__(256) void scan_block(const int* __restrict__ cnt,
                                                  int* __restrict__ rowptr,
                                                  int* __restrict__ bsum, int n) {
    __shared__ int sh[256];
    int tid = threadIdx.x;
    int i = blockIdx.x * 256 + tid;
    int v = (i < n) ? cnt[i] : 0;
    sh[tid] = v;
    __syncthreads();
#pragma unroll
    for (int o = 1; o < 256; o <<= 1) {
        int t = (tid >= o) ? sh[tid - o] : 0;
        __syncthreads();
        sh[tid] += t;
        __syncthreads();
    }
    if (i < n) rowptr[i] = sh[tid] - v;
    if (tid == 255) bsum[blockIdx.x] = sh[255];
}

__global__ __launch_bounds__(256) void scan_bsum(int* __restrict__ bsum, int nb) {
    __shared__ int sh[256];
    __shared__ int carry;
    int tid = threadIdx.x;
    if (tid == 0) carry = 0;
    __syncthreads();
    for (int base = 0; base < nb; base += 256) {
        int i = base + tid;
        int v = (i < nb) ? bsum[i] : 0;
        sh[tid] = v;
        __syncthreads();
#pragma unroll
        for (int o = 1; o < 256; o <<= 1) {
            int t = (tid >= o) ? sh[tid - o] : 0;
            __syncthreads();
            sh[tid] += t;
            __syncthreads();
        }
        int excl = sh[tid] - v + carry;
        int chunk_total = sh[255];
        __syncthreads();
        if (i < nb) bsum[i] = excl;
        if (tid == 0) carry += chunk_total;
        __syncthreads();
    }
}

__global__ __launch_bounds__(256) void scan_add(int* __restrict__ rowptr,
                                                const int* __restrict__ bsum,
                                                int n, int Etot) {
    int i = blockIdx.x * 256 + threadIdx.x;
    if (i < n) rowptr[i] += bsum[blockIdx.x];
    if (i == 0) rowptr[n] = Etot;
}

__global__ __launch_bounds__(256) void fill_csr(const int* __restrict__ src,
                                                const int* __restrict__ dst,
                                                const int* __restrict__ et,
                                                int* __restrict__ cursor,
                                                int* __restrict__ esrc, int E) {
    int e = blockIdx.x * 256 + threadIdx.x;
    if (e < E) {
        int pos = atomicAdd(&cursor[et[e] * N_NODES_C + dst[e]], 1);
        esrc[pos] = src[e];
    }
}

// ---------------------------------------------------------------------------
// conversions to bf16
// ---------------------------------------------------------------------------
__global__ __launch_bounds__(256) void convert_x(const float* __restrict__ x,
                                                 unsigned short* __restrict__ xb, int n4) {
    int i = blockIdx.x * 256 + threadIdx.x;
    if (i >= n4) return;
    float4 v = ((const float4*)x)[i];
    ushort4 o;
    o.x = f2bf(v.x); o.y = f2bf(v.y); o.z = f2bf(v.z); o.w = f2bf(v.w);
    ((ushort4*)xb)[i] = o;
}

// Bt[c][kv] (col-major over virtual K): kv<128 -> root[kv][c]; else W[r][kk][c]
__global__ __launch_bounds__(256) void convert_w(const float* __restrict__ root,
                                                 const float* __restrict__ W,
                                                 unsigned short* __restrict__ Bt) {
    int idx = blockIdx.x * 256 + threadIdx.x;
    if (idx >= FEAT * KTOT) return;
    int c = idx / KTOT;
    int kv = idx - c * KTOT;
    float val;
    if (kv < FEAT) {
        val = root[kv * FEAT + c];
    } else {
        int r = (kv - FEAT) >> 7;
        int kk = (kv - FEAT) & 127;
        val = W[((size_t)r * FEAT + kk) * FEAT + c];
    }
    Bt[idx] = f2bf(val);
}

// ---------------------------------------------------------------------------
// gather: agg[r][local][:] = mean over CSR[r][node] of hb[src][:]  (bf16 out)
// one wave per (relation, node); lane = (edge-slot 0..3, feat-seg 0..15).
// 16B loads, 4 edges in flight, shfl_xor reduction over edge-slots.
// ---------------------------------------------------------------------------
__global__ __launch_bounds__(256) void gather_mean(const unsigned short* __restrict__ hb,
                                                   const int* __restrict__ esrc,
                                                   const int* __restrict__ rowptr,
                                                   const float* __restrict__ inv,
                                                   unsigned short* __restrict__ agg,
                                                   int chunk0, int CL) {
    int w = threadIdx.x >> 6;
    int lane = threadIdx.x & 63;
    int es = lane >> 4;         // edge slot 0..3
    int seg = lane & 15;        // feat segment: feats [seg*8, seg*8+8)
    int local = blockIdx.x * 4 + w;
    int r = blockIdx.y;
    int node = chunk0 + local;
    int lo = rowptr[r * N_NODES_C + node];
    int hi = rowptr[r * N_NODES_C + node + 1];

    float acc[8];
#pragma unroll
    for (int j = 0; j < 8; j++) acc[j] = 0.f;

    for (int e = lo + es; e < hi; e += 4) {
        int s = esrc[e];
        uint4 u = *(const uint4*)(hb + ((size_t)s << 7) + seg * 8);
        union { unsigned int u; float f; } t;
        t.u = u.x << 16;        acc[0] += t.f;
        t.u = u.x & 0xFFFF0000u; acc[1] += t.f;
        t.u = u.y << 16;        acc[2] += t.f;
        t.u = u.y & 0xFFFF0000u; acc[3] += t.f;
        t.u = u.z << 16;        acc[4] += t.f;
        t.u = u.z & 0xFFFF0000u; acc[5] += t.f;
        t.u = u.w << 16;        acc[6] += t.f;
        t.u = u.w & 0xFFFF0000u; acc[7] += t.f;
    }
#pragma unroll
    for (int j = 0; j < 8; j++) {
        acc[j] += __shfl_xor(acc[j], 16, 64);
        acc[j] += __shfl_xor(acc[j], 32, 64);
    }
    if (es == 0) {
        float sc = inv[r * N_NODES_C + node];
        uint4 o;
        o.x = ((unsigned int)f2bf(acc[1] * sc) << 16) | f2bf(acc[0] * sc);
        o.y = ((unsigned int)f2bf(acc[3] * sc) << 16) | f2bf(acc[2] * sc);
        o.z = ((unsigned int)f2bf(acc[5] * sc) << 16) | f2bf(acc[4] * sc);
        o.w = ((unsigned int)f2bf(acc[7] * sc) << 16) | f2bf(acc[6] * sc);
        *(uint4*)(agg + (((size_t)r * CL + local) << 7) + seg * 8) = o;
    }
}

// ---------------------------------------------------------------------------
// MFMA GEMM: C[n][0:128] = relu( A_virt[n][0:768] @ B + bias )
//   A_virt k<128 -> hb[node][k]; k>=128 -> agg[r][local][k%128] (pre-scaled means)
// Block 128 rows x 128 cols, 4 waves in 2x2, wave tile 64x64 (4x4 MFMA tiles).
// ---------------------------------------------------------------------------
__global__ __launch_bounds__(256) void rgcn_gemm(const unsigned short* __restrict__ hb,
                                                 const unsigned short* __restrict__ agg,
                                                 const unsigned short* __restrict__ Bt,
                                                 const float* __restrict__ bias,
                                                 float* __restrict__ outf,
                                                 unsigned short* __restrict__ outb,
                                                 int chunk0, int CL) {
    __shared__ unsigned short As[BM * LDA];
    __shared__ unsigned short Bs[FEAT * LDA];

    const int tid = threadIdx.x;
    const int w = tid >> 6, lane = tid & 63;
    const int wr = w >> 1, wc = w & 1;
    const int brow0 = blockIdx.x * BM;
    const int lq = lane >> 4;
    const int lm = lane & 15;

    f32x4 acc[4][4];
#pragma unroll
    for (int i = 0; i < 4; i++)
#pragma unroll
        for (int j = 0; j < 4; j++) acc[i][j] = (f32x4){0.f, 0.f, 0.f, 0.f};

    const int arow = tid >> 1;
    const int aseg = (tid & 1) * 16;
    int lrow = brow0 + arow;
    if (lrow >= CL) lrow = CL - 1;
    const size_t hbrow = (size_t)(chunk0 + lrow) << 7;

    for (int kb = 0; kb < KTOT; kb += BK) {
        __syncthreads();
        const unsigned short* asrc;
        if (kb < FEAT) {
            asrc = hb + hbrow + kb + aseg;
        } else {
            int r = (kb - FEAT) >> 7;
            int kk = (kb - FEAT) & 127;
            asrc = agg + (((size_t)r * CL + lrow) << 7) + kk + aseg;
        }
        *(float4*)&As[arow * LDA + aseg]     = *(const float4*)(asrc);
        *(float4*)&As[arow * LDA + aseg + 8] = *(const float4*)(asrc + 8);
        const unsigned short* bsrc = Bt + (size_t)arow * KTOT + kb + aseg;
        *(float4*)&Bs[arow * LDA + aseg]     = *(const float4*)(bsrc);
        *(float4*)&Bs[arow * LDA + aseg + 8] = *(const float4*)(bsrc + 8);
        __syncthreads();

        bf16x8 af[4], bf[4];
#pragma unroll
        for (int t = 0; t < 4; t++) {
            int row = wr * 64 + t * 16 + lm;
            af[t] = *(const bf16x8*)&As[row * LDA + lq * 8];
            int col = wc * 64 + t * 16 + lm;
            bf[t] = *(const bf16x8*)&Bs[col * LDA + lq * 8];
        }
#pragma unroll
        for (int i = 0; i < 4; i++)
#pragma unroll
            for (int j = 0; j < 4; j++)
                acc[i][j] = __builtin_amdgcn_mfma_f32_16x16x32_bf16(af[i], bf[j], acc[i][j], 0, 0, 0);
    }

    float bcol[4];
#pragma unroll
    for (int j = 0; j < 4; j++) bcol[j] = bias[wc * 64 + j * 16 + lm];

#pragma unroll
    for (int i = 0; i < 4; i++) {
#pragma unroll
        for (int reg = 0; reg < 4; reg++) {
            int lr = brow0 + wr * 64 + i * 16 + lq * 4 + reg;
            if (lr < CL) {
                size_t grow = (size_t)(chunk0 + lr) << 7;
#pragma unroll
                for (int j = 0; j < 4; j++) {
                    float v = acc[i][j][reg] + bcol[j];
                    v = fmaxf(v, 0.f);
                    int col = wc * 64 + j * 16 + lm;
                    if (outf) outf[grow + col] = v;
                    else outb[grow + col] = f2bf(v);
                }
            }
        }
    }
}

// ---------------------------------------------------------------------------
extern "C" void kernel_launch(void* const* d_in, const int* in_sizes, int n_in,
                              void* d_out, int out_size, void* d_ws, size_t ws_size,
                              hipStream_t stream) {
    const float* x = (const float*)d_in[0];
    const int* ei  = (const int*)d_in[1];
    const int* et  = (const int*)d_in[2];
    const int E = in_sizes[2];
    const int* src  = ei;
    const int* dstp = ei + E;

    // workspace layout:
    //   inv    @ 0           (2,000,000)
    //   rowptr @ 2,097,152   (2,000,004)
    //   esrc   @ 4,194,304   (6,400,000)
    //   xbA    @ 10,616,832  (25,600,000)
    //   xbB    @ 36,306,944  (25,600,000)
    //   agg    @ 61,997,056  (CL*1280 bytes)  [cnt/cursor/bsum alias here]
    //   Bt     @ 61,997,056 + CL*1280 (589,824)
    // CL chosen at runtime from ws_size: 100000 (190.6MB) / 50000 (126.6MB) /
    // 25000 (94.6MB, proven safe: round-2 ran 119.4MB).
    int CL = 25000;
    if (ws_size >= 61997056ull + 100000ull * 1280ull + 589824ull) CL = 100000;
    else if (ws_size >= 61997056ull + 50000ull * 1280ull + 589824ull) CL = 50000;
    const int NCHUNK = N_NODES_C / CL;

    char* ws = (char*)d_ws;
    float* inv             = (float*)ws;
    int*   rowptr          = (int*)(ws + 2097152);
    int*   esrc            = (int*)(ws + 4194304);
    unsigned short* xbA    = (unsigned short*)(ws + 10616832);
    unsigned short* xbB    = (unsigned short*)(ws + 36306944);
    unsigned short* agg    = (unsigned short*)(ws + 61997056);
    unsigned short* BtAll  = (unsigned short*)(ws + 61997056 + (size_t)CL * 1280ull);
    int*   cnt    = (int*)(ws + 61997056);             // alias agg (dead before gathers)
    int*   cursor = (int*)(ws + 61997056 + 2097152);   // alias agg
    int*   bsum   = (int*)(ws + 61997056 + 4194304);   // alias agg

    const int nscan_blocks = (N_TOT + 255) / 256;

    hipMemsetAsync(cnt, 0, (size_t)N_TOT * 4, stream);
    count_edges<<<(E + 255) / 256, 256, 0, stream>>>(dstp, et, cnt, E);
    make_inv<<<(N_TOT + 255) / 256, 256, 0, stream>>>(cnt, inv, N_TOT);
    scan_block<<<nscan_blocks, 256, 0, stream>>>(cnt, rowptr, bsum, N_TOT);
    scan_bsum<<<1, 256, 0, stream>>>(bsum, nscan_blocks);
    scan_add<<<nscan_blocks, 256, 0, stream>>>(rowptr, bsum, N_TOT, E);
    hipMemcpyAsync(cursor, rowptr, (size_t)N_TOT * 4, hipMemcpyDeviceToDevice, stream);
    fill_csr<<<(E + 255) / 256, 256, 0, stream>>>(src, dstp, et, cursor, esrc, E);

    const int n4 = N_NODES_C * FEAT / 4;
    convert_x<<<(n4 + 255) / 256, 256, 0, stream>>>(x, xbA, n4);

    const float* Wp[3] = {(const float*)d_in[3], (const float*)d_in[6], (const float*)d_in[9]};
    const float* Rp[3] = {(const float*)d_in[4], (const float*)d_in[7], (const float*)d_in[10]};
    const float* Bp[3] = {(const float*)d_in[5], (const float*)d_in[8], (const float*)d_in[11]};

    const int nw = FEAT * KTOT;
    for (int l = 0; l < 3; l++)
        convert_w<<<(nw + 255) / 256, 256, 0, stream>>>(Rp[l], Wp[l],
                                                        BtAll + (size_t)l * nw);

    const int gemm_grid = (CL + BM - 1) / BM;
    dim3 ggrid(CL / 4, N_REL_C);

    // layer dataflow (bf16 ping-pong): xbA -> xbB -> xbA -> d_out(fp32)
    for (int l = 0; l < 3; l++) {
        const unsigned short* hin = (l == 1) ? xbB : xbA;
        unsigned short* outb = (l == 0) ? xbB : ((l == 1) ? xbA : nullptr);
        float* outf = (l == 2) ? (float*)d_out : nullptr;
        for (int c = 0; c < NCHUNK; c++) {
            gather_mean<<<ggrid, 256, 0, stream>>>(hin, esrc, rowptr, inv, agg,
                                                   c * CL, CL);
            rgcn_gemm<<<gemm_grid, 256, 0, stream>>>(hin, agg, BtAll + (size_t)l * nw,
                                                     Bp[l], outf, outb, c * CL, CL);
        }
    }
}

// Round 6
// 729.022 us; speedup vs baseline: 7.0199x; 1.2494x over previous
//
#include <hip/hip_runtime.h>

#define N_NODES_C 100000
#define N_REL_C 5
#define N_TOT (N_REL_C * N_NODES_C)
#define FEAT 128
#define KTOT 768        // virtual K = 128 (root) + 5*128 (relations)
#define BM 128          // GEMM block rows
#define GBK 64          // GEMM K-tile

typedef __attribute__((ext_vector_type(8))) short bf16x8;
typedef __attribute__((ext_vector_type(4))) float f32x4;

__device__ inline unsigned short f2bf(float f) {
    union { float f; unsigned int u; } v; v.f = f;
    return (unsigned short)((v.u + 0x7FFFu + ((v.u >> 16) & 1u)) >> 16);
}

// async 16B global->LDS: lds dest = wave-uniform base + lane*16 (m97 pattern)
__device__ __forceinline__ void g2l16(const void* g, void* l) {
    __builtin_amdgcn_global_load_lds((const __attribute__((address_space(1))) unsigned int*)g,
                                     (__attribute__((address_space(3))) unsigned int*)l,
                                     16, 0, 0);
}

// ---------------------------------------------------------------------------
// preprocessing: counts, inv, scan -> CSR grouped by (relation, dst)
// ---------------------------------------------------------------------------
__global__ __launch_bounds__(256) void count_edges(const int* __restrict__ dst,
                                                   const int* __restrict__ et,
                                                   int* __restrict__ cnt, int E) {
    int e = blockIdx.x * 256 + threadIdx.x;
    if (e < E) atomicAdd(&cnt[et[e] * N_NODES_C + dst[e]], 1);
}

__global__ __launch_bounds__(256) void make_inv(const int* __restrict__ cnt,
                                                float* __restrict__ inv, int n) {
    int i = blockIdx.x * 256 + threadIdx.x;
    if (i < n) inv[i] = 1.0f / (float)(cnt[i] > 1 ? cnt[i] : 1);
}

__global__ __launch_bounds__(256) void scan_block(const int* __restrict__ cnt,
                                                  int* __restrict__ rowptr,
                                                  int* __restrict__ bsum, int n) {
    __shared__ int sh[256];
    int tid = threadIdx.x;
    int i = blockIdx.x * 256 + tid;
    int v = (i < n) ? cnt[i] : 0;
    sh[tid] = v;
    __syncthreads();
#pragma unroll
    for (int o = 1; o < 256; o <<= 1) {
        int t = (tid >= o) ? sh[tid - o] : 0;
        __syncthreads();
        sh[tid] += t;
        __syncthreads();
    }
    if (i < n) rowptr[i] = sh[tid] - v;
    if (tid == 255) bsum[blockIdx.x] = sh[255];
}

__global__ __launch_bounds__(256) void scan_bsum(int* __restrict__ bsum, int nb) {
    __shared__ int sh[256];
    __shared__ int carry;
    int tid = threadIdx.x;
    if (tid == 0) carry = 0;
    __syncthreads();
    for (int base = 0; base < nb; base += 256) {
        int i = base + tid;
        int v = (i < nb) ? bsum[i] : 0;
        sh[tid] = v;
        __syncthreads();
#pragma unroll
        for (int o = 1; o < 256; o <<= 1) {
            int t = (tid >= o) ? sh[tid - o] : 0;
            __syncthreads();
            sh[tid] += t;
            __syncthreads();
        }
        int excl = sh[tid] - v + carry;
        int chunk_total = sh[255];
        __syncthreads();
        if (i < nb) bsum[i] = excl;
        if (tid == 0) carry += chunk_total;
        __syncthreads();
    }
}

__global__ __launch_bounds__(256) void scan_add(int* __restrict__ rowptr,
                                                const int* __restrict__ bsum,
                                                int n, int Etot) {
    int i = blockIdx.x * 256 + threadIdx.x;
    if (i < n) rowptr[i] += bsum[blockIdx.x];
    if (i == 0) rowptr[n] = Etot;
}

__global__ __launch_bounds__(256) void fill_csr(const int* __restrict__ src,
                                                const int* __restrict__ dst,
                                                const int* __restrict__ et,
                                                int* __restrict__ cursor,
                                                int* __restrict__ esrc, int E) {
    int e = blockIdx.x * 256 + threadIdx.x;
    if (e < E) {
        int pos = atomicAdd(&cursor[et[e] * N_NODES_C + dst[e]], 1);
        esrc[pos] = src[e];
    }
}

// ---------------------------------------------------------------------------
// conversions to bf16
// ---------------------------------------------------------------------------
__global__ __launch_bounds__(256) void convert_x(const float* __restrict__ x,
                                                 unsigned short* __restrict__ xb, int n4) {
    int i = blockIdx.x * 256 + threadIdx.x;
    if (i >= n4) return;
    float4 v = ((const float4*)x)[i];
    ushort4 o;
    o.x = f2bf(v.x); o.y = f2bf(v.y); o.z = f2bf(v.z); o.w = f2bf(v.w);
    ((ushort4*)xb)[i] = o;
}

// Bt[c][kv] (col-major over virtual K): kv<128 -> root[kv][c]; else W[r][kk][c]
__global__ __launch_bounds__(256) void convert_w(const float* __restrict__ root,
                                                 const float* __restrict__ W,
                                                 unsigned short* __restrict__ Bt) {
    int idx = blockIdx.x * 256 + threadIdx.x;
    if (idx >= FEAT * KTOT) return;
    int c = idx / KTOT;
    int kv = idx - c * KTOT;
    float val;
    if (kv < FEAT) {
        val = root[kv * FEAT + c];
    } else {
        int r = (kv - FEAT) >> 7;
        int kk = (kv - FEAT) & 127;
        val = W[((size_t)r * FEAT + kk) * FEAT + c];
    }
    Bt[idx] = f2bf(val);
}

// ---------------------------------------------------------------------------
// gather: agg[r][local][:] = mean over CSR[r][node] of hb[src][:]  (bf16 out)
// quarter-wave (16 lanes) per (relation, node); lane = feat-seg (16B of row).
// One edge per iteration, full 256B row coalesced; no cross-lane reduction.
// ---------------------------------------------------------------------------
__global__ __launch_bounds__(256) void gather_mean(const unsigned short* __restrict__ hb,
                                                   const int* __restrict__ esrc,
                                                   const int* __restrict__ rowptr,
                                                   const float* __restrict__ inv,
                                                   unsigned short* __restrict__ agg,
                                                   int chunk0, int CL) {
    int qw = threadIdx.x >> 4;       // 0..15 quarter-waves per block
    int seg = threadIdx.x & 15;      // feats [seg*8, seg*8+8)
    int local = blockIdx.x * 16 + qw;
    if (local >= CL) return;
    int r = blockIdx.y;
    int node = chunk0 + local;
    int lo = rowptr[r * N_NODES_C + node];
    int hi = rowptr[r * N_NODES_C + node + 1];

    float acc[8];
#pragma unroll
    for (int j = 0; j < 8; j++) acc[j] = 0.f;

    for (int e = lo; e < hi; e++) {
        int s = esrc[e];
        uint4 u = *(const uint4*)(hb + ((size_t)s << 7) + seg * 8);
        union { unsigned int u; float f; } t;
        t.u = u.x << 16;         acc[0] += t.f;
        t.u = u.x & 0xFFFF0000u; acc[1] += t.f;
        t.u = u.y << 16;         acc[2] += t.f;
        t.u = u.y & 0xFFFF0000u; acc[3] += t.f;
        t.u = u.z << 16;         acc[4] += t.f;
        t.u = u.z & 0xFFFF0000u; acc[5] += t.f;
        t.u = u.w << 16;         acc[6] += t.f;
        t.u = u.w & 0xFFFF0000u; acc[7] += t.f;
    }
    float sc = inv[r * N_NODES_C + node];
    uint4 o;
    o.x = ((unsigned int)f2bf(acc[1] * sc) << 16) | f2bf(acc[0] * sc);
    o.y = ((unsigned int)f2bf(acc[3] * sc) << 16) | f2bf(acc[2] * sc);
    o.z = ((unsigned int)f2bf(acc[5] * sc) << 16) | f2bf(acc[4] * sc);
    o.w = ((unsigned int)f2bf(acc[7] * sc) << 16) | f2bf(acc[6] * sc);
    *(uint4*)(agg + (((size_t)r * CL + local) << 7) + seg * 8) = o;
}

// ---------------------------------------------------------------------------
// MFMA GEMM (m97-style): C[n][0:128] = relu( A_virt[n][0:768] @ B + bias )
//   A_virt k<128 -> hb[node][k]; k>=128 -> agg[r][local][k%128] (pre-scaled means)
// BK=64, global_load_lds(16B) staging into unpadded LDS with chunk-XOR swizzle
// (c ^ (row&7)); reader applies same XOR -> 2-way bank aliasing (free, m136).
// Block 128x128, 4 waves 2x2, wave tile 64x64 (4x4 MFMA 16x16x32 tiles).
// ---------------------------------------------------------------------------
__global__ __launch_bounds__(256) void rgcn_gemm(const unsigned short* __restrict__ hb,
                                                 const unsigned short* __restrict__ agg,
                                                 const unsigned short* __restrict__ Bt,
                                                 const float* __restrict__ bias,
                                                 float* __restrict__ outf,
                                                 unsigned short* __restrict__ outb,
                                                 int chunk0, int CL) {
    __shared__ unsigned short As[BM * GBK];    // 16 KB
    __shared__ unsigned short Bs[FEAT * GBK];  // 16 KB

    const int tid = threadIdx.x;
    const int w = tid >> 6, lane = tid & 63;
    const int wr = w >> 1, wc = w & 1;
    const int lm = lane & 15, lq = lane >> 4;
    const int brow0 = blockIdx.x * BM;

    f32x4 acc[4][4];
#pragma unroll
    for (int i = 0; i < 4; i++)
#pragma unroll
        for (int j = 0; j < 4; j++) acc[i][j] = (f32x4){0.f, 0.f, 0.f, 0.f};

    // staging geometry: 1024 16B-chunks per tile; instr i of wave w covers
    // chunk ids cid = (w*4+i)*64 + lane; cid -> (row = cid>>3, c = cid&7).
    // source chunk is XOR-swizzled: cs = c ^ (row&7).
    size_t hboff[4];   // hb row offset + swizzled chunk (add kb)
    size_t aggoff[4];  // agg row offset + swizzled chunk (add rel term)
    size_t boff[4];    // Bt col offset + swizzled chunk (add kb)
    int ldsbase[4];    // wave-uniform LDS ushort base per instr
#pragma unroll
    for (int i = 0; i < 4; i++) {
        int cid = (w * 4 + i) * 64 + lane;
        int row = cid >> 3;
        int cs = (cid & 7) ^ (row & 7);
        int gr = brow0 + row;
        if (gr >= CL) gr = CL - 1;
        hboff[i]  = ((size_t)(chunk0 + gr) << 7) + cs * 8;
        aggoff[i] = ((size_t)gr << 7) + cs * 8;
        boff[i]   = (size_t)row * KTOT + cs * 8;   // row doubles as col for B
        ldsbase[i] = ((w * 4 + i) * 64) * 8;
    }

    for (int kb = 0; kb < KTOT; kb += GBK) {
        __syncthreads();   // prev-iter LDS reads done before overwrite
        if (kb < FEAT) {
#pragma unroll
            for (int i = 0; i < 4; i++)
                g2l16(hb + hboff[i] + kb, &As[ldsbase[i]]);
        } else {
            size_t reloff = (((size_t)((kb - FEAT) >> 7)) * CL << 7) + (size_t)((kb - FEAT) & 127);
#pragma unroll
            for (int i = 0; i < 4; i++)
                g2l16(agg + aggoff[i] + reloff, &As[ldsbase[i]]);
        }
#pragma unroll
        for (int i = 0; i < 4; i++)
            g2l16(Bt + boff[i] + kb, &Bs[ldsbase[i]]);
        __syncthreads();   // compiler emits vmcnt(0) drain before barrier

#pragma unroll
        for (int h = 0; h < 2; h++) {
            bf16x8 af[4], bf[4];
#pragma unroll
            for (int t = 0; t < 4; t++) {
                int row = wr * 64 + t * 16 + lm;
                int ca = (h * 4 + lq) ^ (row & 7);
                af[t] = *(const bf16x8*)&As[row * GBK + ca * 8];
                int col = wc * 64 + t * 16 + lm;
                int cb = (h * 4 + lq) ^ (col & 7);
                bf[t] = *(const bf16x8*)&Bs[col * GBK + cb * 8];
            }
#pragma unroll
            for (int i = 0; i < 4; i++)
#pragma unroll
                for (int j = 0; j < 4; j++)
                    acc[i][j] = __builtin_amdgcn_mfma_f32_16x16x32_bf16(af[i], bf[j], acc[i][j], 0, 0, 0);
        }
    }

    float bcol[4];
#pragma unroll
    for (int j = 0; j < 4; j++) bcol[j] = bias[wc * 64 + j * 16 + lm];

#pragma unroll
    for (int i = 0; i < 4; i++) {
#pragma unroll
        for (int reg = 0; reg < 4; reg++) {
            int lr = brow0 + wr * 64 + i * 16 + lq * 4 + reg;
            if (lr < CL) {
                size_t grow = (size_t)(chunk0 + lr) << 7;
#pragma unroll
                for (int j = 0; j < 4; j++) {
                    float v = acc[i][j][reg] + bcol[j];
                    v = fmaxf(v, 0.f);
                    int col = wc * 64 + j * 16 + lm;
                    if (outf) outf[grow + col] = v;
                    else outb[grow + col] = f2bf(v);
                }
            }
        }
    }
}

// ---------------------------------------------------------------------------
extern "C" void kernel_launch(void* const* d_in, const int* in_sizes, int n_in,
                              void* d_out, int out_size, void* d_ws, size_t ws_size,
                              hipStream_t stream) {
    const float* x = (const float*)d_in[0];
    const int* ei  = (const int*)d_in[1];
    const int* et  = (const int*)d_in[2];
    const int E = in_sizes[2];
    const int* src  = ei;
    const int* dstp = ei + E;

    // workspace layout:
    //   inv    @ 0           (2,000,000)
    //   rowptr @ 2,097,152   (2,000,004)
    //   esrc   @ 4,194,304   (6,400,000)
    //   xbA    @ 10,616,832  (25,600,000)
    //   xbB    @ 36,306,944  (25,600,000)
    //   agg    @ 61,997,056  (CL*1280 bytes)  [cnt/cursor/bsum alias here]
    //   Bt     @ 61,997,056 + CL*1280 (589,824)
    // CL chosen at runtime from ws_size (round-4 proved >=190.6 MB works).
    int CL = 25000;
    if (ws_size >= 61997056ull + 100000ull * 1280ull + 589824ull) CL = 100000;
    else if (ws_size >= 61997056ull + 50000ull * 1280ull + 589824ull) CL = 50000;
    const int NCHUNK = N_NODES_C / CL;

    char* ws = (char*)d_ws;
    float* inv             = (float*)ws;
    int*   rowptr          = (int*)(ws + 2097152);
    int*   esrc            = (int*)(ws + 4194304);
    unsigned short* xbA    = (unsigned short*)(ws + 10616832);
    unsigned short* xbB    = (unsigned short*)(ws + 36306944);
    unsigned short* agg    = (unsigned short*)(ws + 61997056);
    unsigned short* BtAll  = (unsigned short*)(ws + 61997056 + (size_t)CL * 1280ull);
    int*   cnt    = (int*)(ws + 61997056);             // alias agg (dead before gathers)
    int*   cursor = (int*)(ws + 61997056 + 2097152);   // alias agg
    int*   bsum   = (int*)(ws + 61997056 + 4194304);   // alias agg

    const int nscan_blocks = (N_TOT + 255) / 256;

    hipMemsetAsync(cnt, 0, (size_t)N_TOT * 4, stream);
    count_edges<<<(E + 255) / 256, 256, 0, stream>>>(dstp, et, cnt, E);
    make_inv<<<(N_TOT + 255) / 256, 256, 0, stream>>>(cnt, inv, N_TOT);
    scan_block<<<nscan_blocks, 256, 0, stream>>>(cnt, rowptr, bsum, N_TOT);
    scan_bsum<<<1, 256, 0, stream>>>(bsum, nscan_blocks);
    scan_add<<<nscan_blocks, 256, 0, stream>>>(rowptr, bsum, N_TOT, E);
    hipMemcpyAsync(cursor, rowptr, (size_t)N_TOT * 4, hipMemcpyDeviceToDevice, stream);
    fill_csr<<<(E + 255) / 256, 256, 0, stream>>>(src, dstp, et, cursor, esrc, E);

    const int n4 = N_NODES_C * FEAT / 4;
    convert_x<<<(n4 + 255) / 256, 256, 0, stream>>>(x, xbA, n4);

    const float* Wp[3] = {(const float*)d_in[3], (const float*)d_in[6], (const float*)d_in[9]};
    const float* Rp[3] = {(const float*)d_in[4], (const float*)d_in[7], (const float*)d_in[10]};
    const float* Bp[3] = {(const float*)d_in[5], (const float*)d_in[8], (const float*)d_in[11]};

    const int nw = FEAT * KTOT;
    for (int l = 0; l < 3; l++)
        convert_w<<<(nw + 255) / 256, 256, 0, stream>>>(Rp[l], Wp[l],
                                                        BtAll + (size_t)l * nw);

    const int gemm_grid = (CL + BM - 1) / BM;
    dim3 ggrid((CL + 15) / 16, N_REL_C);

    // layer dataflow (bf16 ping-pong): xbA -> xbB -> xbA -> d_out(fp32)
    for (int l = 0; l < 3; l++) {
        const unsigned short* hin = (l == 1) ? xbB : xbA;
        unsigned short* outb = (l == 0) ? xbB : ((l == 1) ? xbA : nullptr);
        float* outf = (l == 2) ? (float*)d_out : nullptr;
        for (int c = 0; c < NCHUNK; c++) {
            gather_mean<<<ggrid, 256, 0, stream>>>(hin, esrc, rowptr, inv, agg,
                                                   c * CL, CL);
            rgcn_gemm<<<gemm_grid, 256, 0, stream>>>(hin, agg, BtAll + (size_t)l * nw,
                                                     Bp[l], outf, outb, c * CL, CL);
        }
    }
}